// Round 7
// baseline (1574.268 us; speedup 1.0000x reference)
//
#include <hip/hip_runtime.h>
#include <stdint.h>

#define NN 20000
#define EE 320000
#define FF 64
#define ROW 128              // B*F
#define KTOP 160000
#define NEG_SLOPE 0.2f
#define LN_EPS 1e-5f
#define H16BINS 16384        // (u>>12) - (120<<11), clamped: covers alpha in [2^-7, 1]
#define HBASE (120 << 11)
#define CCAP 4096

__device__ __forceinline__ unsigned int bin_of(unsigned int u) {
  int b = (int)(u >> 12) - HBASE;
  b = b < 0 ? 0 : (b > (H16BINS - 1) ? (H16BINS - 1) : b);
  return (unsigned int)b;
}

// ---------- precompute: rel table [4096] and wa[4][128] ----------
__global__ void precompute_kernel(const float* __restrict__ query,
                                  const float* __restrict__ rel_w,
                                  const float* __restrict__ rel_b,
                                  const float* __restrict__ W,
                                  const float* __restrict__ a,
                                  float* __restrict__ relflat,
                                  float* __restrict__ wa4) {
  int t = blockIdx.x * blockDim.x + threadIdx.x;
  if (t < 4096) {
    int bq = t >> 11, c = t & 2047;
    const float* q = query + bq * FF;
    const float* w = rel_w + (size_t)c * FF;
    float s = rel_b[c];
#pragma unroll
    for (int f = 0; f < FF; f++) s += q[f] * w[f];
    relflat[t] = s;
  }
  if (t < 512) {
    int i = t >> 7, j = t & 127;
    const float* av = a + i * FF;
    const float* w = W + (size_t)j * FF;
    float s = 0.f;
#pragma unroll
    for (int f = 0; f < FF; f++) s += w[f] * av[f];
    wa4[t] = s;
  }
}

// ---------- CSR builds (once per launch) ----------
__global__ void degcnt_kernel(const int* __restrict__ esrc, const int* __restrict__ edst,
                              unsigned int* __restrict__ deg_s, unsigned int* __restrict__ deg_d) {
  int e = blockIdx.x * blockDim.x + threadIdx.x;
  if (e < EE) {
    atomicAdd(deg_s + esrc[e], 1u);
    atomicAdd(deg_d + edst[e], 1u);
  }
}

__global__ void scan_kernel(const unsigned int* __restrict__ deg,
                            unsigned int* __restrict__ rowptr,
                            unsigned int* __restrict__ rowfill) {
  __shared__ unsigned int sh[1024];
  int t = threadIdx.x;
  const int PER = 20;  // 1024*20 >= NN
  unsigned int loc[PER];
  unsigned int sum = 0;
  int base = t * PER;
#pragma unroll
  for (int i = 0; i < PER; i++) {
    int n = base + i;
    unsigned int d = (n < NN) ? deg[n] : 0u;
    loc[i] = sum;
    sum += d;
  }
  sh[t] = sum;
  __syncthreads();
  for (int o = 1; o < 1024; o <<= 1) {
    unsigned int v = (t >= o) ? sh[t - o] : 0u;
    __syncthreads();
    sh[t] += v;
    __syncthreads();
  }
  unsigned int excl = sh[t] - sum;
#pragma unroll
  for (int i = 0; i < PER; i++) {
    int n = base + i;
    if (n < NN) {
      unsigned int rp = excl + loc[i];
      rowptr[n] = rp;
      rowfill[n] = rp;
    }
  }
  if (t == 1023) rowptr[NN] = EE;
}

// fill both CSRs; src entries packed as e | (r<<19)
__global__ void fill_kernel(const int* __restrict__ esrc, const int* __restrict__ edst,
                            const int* __restrict__ rix,
                            unsigned int* __restrict__ rowfill_s, unsigned int* __restrict__ rowfill_d,
                            unsigned int* __restrict__ cspack_s, int* __restrict__ csre_d) {
  int e = blockIdx.x * blockDim.x + threadIdx.x;
  if (e < EE) {
    unsigned int r = (unsigned int)rix[e];
    unsigned int ss = atomicAdd(rowfill_s + esrc[e], 1u);
    cspack_s[ss] = (unsigned int)e | (r << 19);
    unsigned int sd = atomicAdd(rowfill_d + edst[e], 1u);
    csre_d[sd] = e;
  }
}

// packed_d[p] = src | (r<<20) in dst-CSR order; pos_d[e] = p (inverse perm)
__global__ void gatherd_kernel(const int* __restrict__ csre_d, const int* __restrict__ esrc,
                               const int* __restrict__ rix, unsigned int* __restrict__ packed_d,
                               unsigned int* __restrict__ pos_d) {
  int p = blockIdx.x * blockDim.x + threadIdx.x;
  if (p < EE) {
    int e = csre_d[p];
    packed_d[p] = (unsigned int)esrc[e] | ((unsigned int)rix[e] << 20);
    pos_d[e] = (unsigned int)p;
  }
}

// rewrite cspack_s: replace embedded e with dst-CSR position (both < 2^19)
__global__ void repack_kernel(unsigned int* __restrict__ cspack_s,
                              const unsigned int* __restrict__ pos_d) {
  int i = blockIdx.x * blockDim.x + threadIdx.x;
  if (i < EE) {
    unsigned int cs = cspack_s[i];
    cspack_s[i] = pos_d[cs & 0x7FFFFu] | (cs & 0xFFF80000u);
  }
}

// ---------- init: racc0 and nodewa ----------
__global__ void readout_kernel(const float* __restrict__ x, float* __restrict__ racc) {
  int j = threadIdx.x;  // 0..127
  float acc = 0.f;
  for (int n = blockIdx.x; n < NN; n += gridDim.x) acc += x[(size_t)n * ROW + j];
  atomicAdd(racc + j, acc);
}

__global__ void nodewa_kernel(const float* __restrict__ x, const float* __restrict__ wa,
                              float* __restrict__ nodewa) {
  int wave = threadIdx.x >> 6, lane = threadIdx.x & 63;
  float w0 = wa[lane], w1 = wa[64 + lane];
  for (int n = blockIdx.x * 4 + wave; n < NN; n += gridDim.x * 4) {
    float s = x[(size_t)n * ROW + lane] * w0 + x[(size_t)n * ROW + 64 + lane] * w1;
#pragma unroll
    for (int off = 32; off > 0; off >>= 1) s += __shfl_xor(s, off, 64);
    if (lane == 0) nodewa[n] = s;
  }
}

// ---------- per-src softmax; alpha written in dst-CSR order; 14-bit LDS hist ----------
// state: [0]=bin [1]=krem [2]=T [3]=need [4]=spare [5]=candCnt
__global__ __launch_bounds__(256) void alpha_csr_kernel(
    const unsigned int* __restrict__ rowptr_s, const unsigned int* __restrict__ cspack_s,
    const float* __restrict__ nodewa, const float* __restrict__ relflat,
    const float* __restrict__ wa, float* __restrict__ alpha_d,
    unsigned int* __restrict__ hist16, unsigned int* __restrict__ state) {
  __shared__ float relwa_sh[32];
  __shared__ unsigned int h16[H16BINS];  // 64 KB
  int t = threadIdx.x;
  for (int i = t; i < H16BINS; i += 256) h16[i] = 0u;
  if (t < 32) {
    float s = 0.f;
    const float4* rf = (const float4*)(relflat + t * ROW);
    const float4* wf = (const float4*)wa;
#pragma unroll 8
    for (int j = 0; j < 32; j++) {
      float4 r4 = rf[j], w4 = wf[j];
      s += r4.x * w4.x + r4.y * w4.y + r4.z * w4.z + r4.w * w4.w;
    }
    relwa_sh[t] = s;
  }
  if (blockIdx.x == 0 && t == 255) { state[0] = 0u; state[1] = KTOP; }
  __syncthreads();
  int n = blockIdx.x * 256 + t;
  if (n < NN) {
    unsigned int p0 = rowptr_s[n], p1 = rowptr_s[n + 1];
    float nw = nodewa[n];
    float denom = 0.f;
    for (unsigned int p = p0; p < p1; p++) {
      unsigned int cs = cspack_s[p];
      float v = nw + relwa_sh[cs >> 19];
      v = v > 0.f ? v : NEG_SLOPE * v;
      denom += expf(v);
    }
    float inv = 1.0f / denom;
    for (unsigned int p = p0; p < p1; p++) {
      unsigned int cs = cspack_s[p];
      float v = nw + relwa_sh[cs >> 19];
      v = v > 0.f ? v : NEG_SLOPE * v;
      float av = expf(v) * inv;
      alpha_d[cs & 0x7FFFFu] = av;
      atomicAdd(&h16[bin_of(__float_as_uint(av))], 1u);
    }
  }
  __syncthreads();
  for (int i = t; i < H16BINS; i += 256) {
    unsigned int c = h16[i];
    if (c) atomicAdd(hist16 + i, c);
  }
}

// ---------- select threshold bin over 16384 bins (1 block, 1024 threads) ----------
__global__ void sel16_kernel(unsigned int* __restrict__ state, const unsigned int* __restrict__ hist16) {
  __shared__ unsigned int sh[1024];
  int t = threadIdx.x;
  unsigned int s = 0;
  const unsigned int* hp = hist16 + t * (H16BINS / 1024);
#pragma unroll
  for (int i = 0; i < H16BINS / 1024; i++) s += hp[i];
  sh[t] = s;
  __syncthreads();
  for (int o = 1; o < 1024; o <<= 1) {
    unsigned int v = (t >= o) ? sh[t - o] : 0u;
    __syncthreads();
    sh[t] += v;
    __syncthreads();
  }
  unsigned int incl = sh[t];
  unsigned int total = sh[1023];
  unsigned int krem = state[1];
  unsigned int cumAbove = total - incl;
  if (t == 0) state[5] = 0u;
  if (cumAbove < krem && cumAbove + s >= krem) {
    unsigned int cum = cumAbove;
    for (int b = H16BINS / 1024 - 1; b >= 0; b--) {
      unsigned int c = hist16[t * (H16BINS / 1024) + b];
      if (cum + c >= krem) {
        state[0] = (unsigned int)(t * (H16BINS / 1024) + b);
        state[1] = krem - cum;
        break;
      }
      cum += c;
    }
  }
}

__device__ __forceinline__ int wave_append(unsigned int* ctr, bool pred) {
  int lane = threadIdx.x & 63;
  unsigned long long m = __ballot(pred);
  if (m == 0ULL) return -1;
  int leader = __ffsll((unsigned long long)m) - 1;
  int base = 0;
  if (lane == leader) base = (int)atomicAdd(ctr, (unsigned int)__popcll(m));
  base = __shfl(base, leader, 64);
  if (!pred) return -1;
  unsigned long long below = m & ((1ULL << lane) - 1ULL);
  return base + (int)__popcll(below);
}

// ---------- collect boundary-bin candidates (tiny count) ----------
__global__ void cand_kernel(const float* __restrict__ alpha_d, unsigned int* __restrict__ state,
                            int* __restrict__ cand_p) {
  int p = blockIdx.x * blockDim.x + threadIdx.x;
  bool match = false;
  if (p < EE) {
    unsigned int u = __float_as_uint(alpha_d[p]);
    match = (bin_of(u) == state[0]);
  }
  int pos = wave_append(state + 5, match);
  if (match && pos < CCAP) cand_p[pos] = p;
}

// ---------- exact threshold + tie-break within boundary bin (1 block) ----------
__global__ void final_kernel(float* __restrict__ alpha_d, const int* __restrict__ csre_d,
                             const int* __restrict__ cand_p, unsigned int* __restrict__ state) {
  __shared__ unsigned int su[CCAP];
  __shared__ int sp[CCAP];
  __shared__ unsigned int sT, sNeed;
  int t = threadIdx.x;
  unsigned int cnt = state[5];
  if (cnt > CCAP) cnt = CCAP;
  unsigned int krem = state[1];
  if (t == 0) { sT = 0u; sNeed = 0xFFFFFFFFu; }
  for (unsigned int i = t; i < cnt; i += 256) {
    int p = cand_p[i];
    sp[i] = p;
    su[i] = __float_as_uint(alpha_d[p]);
  }
  __syncthreads();
  // find T = krem-th largest within bin (all u==T are in this bin by construction)
  for (unsigned int i = t; i < cnt; i += 256) {
    unsigned int ui = su[i];
    unsigned int gt = 0, eq = 0;
    for (unsigned int j = 0; j < cnt; j++) {
      unsigned int uj = su[j];
      gt += (uj > ui) ? 1u : 0u;
      eq += (uj == ui) ? 1u : 0u;
    }
    if (gt < krem && gt + eq >= krem) { sT = ui; sNeed = krem - gt; }
  }
  __syncthreads();
  unsigned int T = sT, need = sNeed;
  if (t == 0) { state[2] = T; state[3] = need; }
  // ties at T: keep lowest original edge index first (jax.lax.top_k order)
  for (unsigned int i = t; i < cnt; i += 256) {
    if (su[i] == T) {
      int e_i = csre_d[sp[i]];
      unsigned int rank = 0;
      for (unsigned int j = 0; j < cnt; j++) {
        if (su[j] == T) {
          int e_j = csre_d[sp[j]];
          rank += (e_j < e_i) ? 1u : 0u;
        }
      }
      if (rank >= need) alpha_d[sp[i]] = 0.f;  // excluded tie -> fails u>=T test
    }
  }
}

// ---------- gather-reduce update: 4 edges x 16 lanes per wave, fused top-k test ----------
__global__ __launch_bounds__(256) void update_kernel(const unsigned int* __restrict__ rowptr_d,
                                                     const unsigned int* __restrict__ packed_d,
                                                     const float* __restrict__ alpha_d,
                                                     const unsigned int* __restrict__ state,
                                                     const float* __restrict__ x,
                                                     const float* __restrict__ relflat,
                                                     float* __restrict__ upd,
                                                     float* __restrict__ racc_next) {
  __shared__ float relf[32 * 132];
  int t = threadIdx.x;
  if (blockIdx.x == 0 && t < 128) racc_next[t] = 0.f;
#pragma unroll
  for (int i = 0; i < 4; i++) {
    int q = t + i * 256;                 // float4 idx 0..1023
    int r = q >> 5, kq = q & 31;
    float4 v = ((const float4*)relflat)[q];
    *(float4*)(relf + r * 132 + kq * 4) = v;
  }
  __syncthreads();
  unsigned int T = state[2];
  int wave = t >> 6, lane = t & 63;
  int g = lane >> 4, l = lane & 15;
  int n = blockIdx.x * 4 + wave;
  if (n >= NN) return;
  unsigned int p0 = rowptr_d[n], p1 = rowptr_d[n + 1];
  float4 A0 = {0.f, 0.f, 0.f, 0.f}, A1 = {0.f, 0.f, 0.f, 0.f};
  for (unsigned int base = p0 + g; base < p1; base += 4) {
    float w = alpha_d[base];
    if (__float_as_uint(w) < T) continue;   // top-k mask (zeroed ties fail too)
    unsigned int up = packed_d[base];
    unsigned int src = up & 0xFFFFFu;
    unsigned int r = up >> 20;
    const float* xr = x + (size_t)src * ROW + l * 8;
    const float* rr = relf + r * 132 + l * 8;
    float4 xv0 = *(const float4*)xr;
    float4 xv1 = *(const float4*)(xr + 4);
    float4 rv0 = *(const float4*)rr;
    float4 rv1 = *(const float4*)(rr + 4);
    A0.x += w * (xv0.x + rv0.x); A0.y += w * (xv0.y + rv0.y);
    A0.z += w * (xv0.z + rv0.z); A0.w += w * (xv0.w + rv0.w);
    A1.x += w * (xv1.x + rv1.x); A1.y += w * (xv1.y + rv1.y);
    A1.z += w * (xv1.z + rv1.z); A1.w += w * (xv1.w + rv1.w);
  }
#pragma unroll
  for (int off = 16; off <= 32; off <<= 1) {
    A0.x += __shfl_xor(A0.x, off, 64); A0.y += __shfl_xor(A0.y, off, 64);
    A0.z += __shfl_xor(A0.z, off, 64); A0.w += __shfl_xor(A0.w, off, 64);
    A1.x += __shfl_xor(A1.x, off, 64); A1.y += __shfl_xor(A1.y, off, 64);
    A1.z += __shfl_xor(A1.z, off, 64); A1.w += __shfl_xor(A1.w, off, 64);
  }
  if (g == 0) {
    const float* xn = x + (size_t)n * ROW + l * 8;
    float4 xs0 = *(const float4*)xn;
    float4 xs1 = *(const float4*)(xn + 4);
    float4 o0 = {A0.x + xs0.x, A0.y + xs0.y, A0.z + xs0.z, A0.w + xs0.w};
    float4 o1 = {A1.x + xs1.x, A1.y + xs1.y, A1.z + xs1.z, A1.w + xs1.w};
    float* on = upd + (size_t)n * ROW + l * 8;
    *(float4*)on = o0;
    *(float4*)(on + 4) = o1;
  }
}

// ---------- node GEMM: [64 rows x 128] @ [128 x 64] + trt + LN + ELU + residual ----------
__global__ __launch_bounds__(256) void node_gemm_kernel(const float* __restrict__ upd,
                                                        const float* __restrict__ layer_w,
                                                        const float* __restrict__ layer_b,
                                                        const float* __restrict__ racc_cur,
                                                        const float* __restrict__ tr_w,
                                                        const float* __restrict__ tr_b,
                                                        const float* __restrict__ ln_g,
                                                        const float* __restrict__ ln_b,
                                                        float* __restrict__ x,
                                                        const float* __restrict__ wa_next,
                                                        float* __restrict__ nodewa,
                                                        float* __restrict__ racc_next) {
  __shared__ float As[64 * 132];
  __shared__ float Ws[64 * 132];
  __shared__ float trt_sh[128];
  __shared__ float racc_sh[128];
  __shared__ float nodewa_sh[32];
  int t = threadIdx.x;
  int n0 = blockIdx.x * 32;
  // per-block trt (readout linear) with layer_b folded in
  if (t < 128) {
    int b = t >> 6, f = t & 63;
    const float invN = 1.0f / (float)NN;
    float s = tr_b[f] + layer_b[f];
    const float* rr = racc_cur + b * 64;
    const float* tw = tr_w + f * 64;
#pragma unroll 16
    for (int gg = 0; gg < 64; gg++) s += rr[gg] * invN * tw[gg];
    trt_sh[t] = s;
    racc_sh[t] = 0.f;
  }
  if (t < 32) nodewa_sh[t] = 0.f;
  // stage A = [x | upd] rows, stride 132
#pragma unroll
  for (int i = 0; i < 4; i++) {
    int v = t + i * 256;                  // 0..1023 float4s
    int nl = v >> 5, i4 = v & 31;
    int b = i4 >> 4, kq = i4 & 15;
    int m = nl * 2 + b;
    float4 xv = ((const float4*)x)[n0 * 32 + v];
    *(float4*)(As + m * 132 + kq * 4) = xv;
  }
#pragma unroll
  for (int i = 0; i < 4; i++) {
    int v = t + i * 256;
    int nl = v >> 5, i4 = v & 31;
    int b = i4 >> 4, kq = i4 & 15;
    int m = nl * 2 + b;
    float4 uv = ((const float4*)upd)[n0 * 32 + v];
    *(float4*)(As + m * 132 + 64 + kq * 4) = uv;
  }
  // stage W swizzled: quad q of row f at position q ^ ((f>>2)&7)
#pragma unroll
  for (int i = 0; i < 8; i++) {
    int Q = t + i * 256;                  // 0..2047
    int f = Q >> 5, q = Q & 31;
    float4 wv = ((const float4*)layer_w)[Q];
    *(float4*)(Ws + f * 132 + ((q ^ ((f >> 2) & 7)) << 2)) = wv;
  }
  __syncthreads();
  int tx = t & 15, ty = t >> 4;
  float acc[4][4] = {};
  const float* Abase = As + (ty * 4) * 132;
  const float* Wbase = Ws + (tx * 4) * 132;
  int wswz = tx & 7;
#pragma unroll 4
  for (int kq = 0; kq < 32; kq++) {
    float4 a0 = *(const float4*)(Abase + 0 * 132 + kq * 4);
    float4 a1 = *(const float4*)(Abase + 1 * 132 + kq * 4);
    float4 a2 = *(const float4*)(Abase + 2 * 132 + kq * 4);
    float4 a3 = *(const float4*)(Abase + 3 * 132 + kq * 4);
    int wq = (kq ^ wswz) << 2;
    float4 w0 = *(const float4*)(Wbase + 0 * 132 + wq);
    float4 w1 = *(const float4*)(Wbase + 1 * 132 + wq);
    float4 w2 = *(const float4*)(Wbase + 2 * 132 + wq);
    float4 w3 = *(const float4*)(Wbase + 3 * 132 + wq);
#define DOT4(A, W) (A.x * W.x + A.y * W.y + A.z * W.z + A.w * W.w)
    acc[0][0] += DOT4(a0, w0); acc[0][1] += DOT4(a0, w1); acc[0][2] += DOT4(a0, w2); acc[0][3] += DOT4(a0, w3);
    acc[1][0] += DOT4(a1, w0); acc[1][1] += DOT4(a1, w1); acc[1][2] += DOT4(a1, w2); acc[1][3] += DOT4(a1, w3);
    acc[2][0] += DOT4(a2, w0); acc[2][1] += DOT4(a2, w1); acc[2][2] += DOT4(a2, w2); acc[2][3] += DOT4(a2, w3);
    acc[3][0] += DOT4(a3, w0); acc[3][1] += DOT4(a3, w1); acc[3][2] += DOT4(a3, w2); acc[3][3] += DOT4(a3, w3);
#undef DOT4
  }
  // add trt (+layer_b); rows m = ty*4+r, b = r&1
#pragma unroll
  for (int r = 0; r < 4; r++) {
    const float* tp = trt_sh + ((r & 1) << 6) + tx * 4;
#pragma unroll
    for (int c = 0; c < 4; c++) acc[r][c] += tp[c];
  }
  // LN stats over 64 f: reduce across 16 tx lanes
  float s[4], qq[4];
#pragma unroll
  for (int r = 0; r < 4; r++) {
    s[r] = acc[r][0] + acc[r][1] + acc[r][2] + acc[r][3];
    qq[r] = acc[r][0] * acc[r][0] + acc[r][1] * acc[r][1] + acc[r][2] * acc[r][2] + acc[r][3] * acc[r][3];
  }
#pragma unroll
  for (int off = 1; off < 16; off <<= 1) {
#pragma unroll
    for (int r = 0; r < 4; r++) {
      s[r] += __shfl_xor(s[r], off, 64);
      qq[r] += __shfl_xor(qq[r], off, 64);
    }
  }
  float4 g4 = ((const float4*)ln_g)[tx];
  float4 b4 = ((const float4*)ln_b)[tx];
  float4 wn = ((const float4*)wa_next)[tx];        // b=0 cols
  float4 wn1 = ((const float4*)wa_next)[16 + tx];  // b=1 cols
  const float invF = 1.0f / (float)FF;
  float nwc[2] = {0.f, 0.f};  // per local node (ty*2, ty*2+1)
#pragma unroll
  for (int r = 0; r < 4; r++) {
    float mu = s[r] * invF;
    float var = qq[r] * invF - mu * mu;
    float rstd = 1.0f / sqrtf(var + LN_EPS);
    int m = ty * 4 + r;
    int nl = m >> 1, b = m & 1;
    // residual x from global (still old values)
    float4 xo = ((const float4*)x)[(n0 + nl) * 32 + b * 16 + tx];
    float o0 = (acc[r][0] - mu) * rstd * g4.x + b4.x;
    float o1 = (acc[r][1] - mu) * rstd * g4.y + b4.y;
    float o2 = (acc[r][2] - mu) * rstd * g4.z + b4.z;
    float o3 = (acc[r][3] - mu) * rstd * g4.w + b4.w;
    float4 y;
    y.x = (o0 > 0.f ? o0 : expm1f(o0)) + xo.x;
    y.y = (o1 > 0.f ? o1 : expm1f(o1)) + xo.y;
    y.z = (o2 > 0.f ? o2 : expm1f(o2)) + xo.z;
    y.w = (o3 > 0.f ? o3 : expm1f(o3)) + xo.w;
    ((float4*)x)[(n0 + nl) * 32 + b * 16 + tx] = y;
    // racc accumulation
    float* rs = racc_sh + (b << 6) + tx * 4;
    atomicAdd(rs + 0, y.x); atomicAdd(rs + 1, y.y);
    atomicAdd(rs + 2, y.z); atomicAdd(rs + 3, y.w);
    // nodewa contribution
    float4 w = b ? wn1 : wn;
    nwc[r >> 1] += y.x * w.x + y.y * w.y + y.z * w.z + y.w * w.w;
  }
  atomicAdd(&nodewa_sh[ty * 2 + 0], nwc[0]);
  atomicAdd(&nodewa_sh[ty * 2 + 1], nwc[1]);
  __syncthreads();
  if (t < 128) atomicAdd(racc_next + t, racc_sh[t]);
  if (t < 32) nodewa[n0 + t] = nodewa_sh[t];
}

extern "C" void kernel_launch(void* const* d_in, const int* in_sizes, int n_in,
                              void* d_out, int out_size, void* d_ws, size_t ws_size,
                              hipStream_t stream) {
  const int* ei = (const int*)d_in[0];
  const int* esrc = ei;
  const int* edst = ei + EE;
  const int* rix = (const int*)d_in[1];
  const float* boundary = (const float*)d_in[2];
  const float* query = (const float*)d_in[3];
  const float* rel_w = (const float*)d_in[4];
  const float* rel_b = (const float*)d_in[5];
  const float* layer_w = (const float*)d_in[6];
  const float* layer_b = (const float*)d_in[7];
  const float* tr_w = (const float*)d_in[8];
  const float* tr_b = (const float*)d_in[9];
  const float* Wm = (const float*)d_in[10];
  const float* av = (const float*)d_in[11];
  const float* ln_g = (const float*)d_in[12];
  const float* ln_b = (const float*)d_in[13];
  float* x = (float*)d_out;

  char* ws = (char*)d_ws;
  size_t off = 0;
  auto allocf = [&](size_t n) -> float* {
    float* p = (float*)(ws + off);
    off += ((n * 4 + 255) / 256) * 256;
    return p;
  };
  auto allocu = [&](size_t n) -> unsigned int* {
    unsigned int* p = (unsigned int*)(ws + off);
    off += ((n * 4 + 255) / 256) * 256;
    return p;
  };
  float* relflat = allocf(4096);
  float* wa4 = allocf(512);
  float* alpha_d = allocf(EE);       // alpha in dst-CSR order
  float* upd = allocf((size_t)NN * ROW);
  float* racc0 = allocf(128);
  float* racc1 = allocf(128);
  float* nodewa = allocf(NN);
  unsigned int* hist16 = allocu(H16BINS);
  unsigned int* state = allocu(8);
  unsigned int* deg_s = allocu(NN);
  unsigned int* deg_d = allocu(NN);
  unsigned int* rowptr_s = allocu(NN + 1);
  unsigned int* rowptr_d = allocu(NN + 1);
  unsigned int* rowfill_s = allocu(NN);
  unsigned int* rowfill_d = allocu(NN);
  unsigned int* cspack_s = allocu(EE);
  int* csre_d = (int*)allocu(EE);
  unsigned int* packed_d = allocu(EE);
  unsigned int* pos_d = allocu(EE);
  int* cand_p = (int*)allocu(CCAP);
  float* rbuf[2] = {racc0, racc1};

  hipMemcpyAsync(x, boundary, (size_t)NN * ROW * 4, hipMemcpyDeviceToDevice, stream);
  hipMemsetAsync(deg_s, 0, NN * 4, stream);
  hipMemsetAsync(deg_d, 0, NN * 4, stream);
  hipMemsetAsync(racc0, 0, 128 * 4, stream);
  precompute_kernel<<<16, 256, 0, stream>>>(query, rel_w, rel_b, Wm, av, relflat, wa4);

  // CSR builds (edge_index constant for this launch)
  degcnt_kernel<<<EE / 256, 256, 0, stream>>>(esrc, edst, deg_s, deg_d);
  scan_kernel<<<1, 1024, 0, stream>>>(deg_s, rowptr_s, rowfill_s);
  scan_kernel<<<1, 1024, 0, stream>>>(deg_d, rowptr_d, rowfill_d);
  fill_kernel<<<EE / 256, 256, 0, stream>>>(esrc, edst, rix, rowfill_s, rowfill_d, cspack_s, csre_d);
  gatherd_kernel<<<EE / 256, 256, 0, stream>>>(csre_d, esrc, rix, packed_d, pos_d);
  repack_kernel<<<EE / 256, 256, 0, stream>>>(cspack_s, pos_d);

  // iter-0 readout sum and nodewa
  readout_kernel<<<256, 128, 0, stream>>>(x, racc0);
  nodewa_kernel<<<1250, 256, 0, stream>>>(x, wa4, nodewa);

  for (int it = 0; it < 4; it++) {
    float* rcur = rbuf[it & 1];
    float* rnxt = rbuf[(it + 1) & 1];
    const float* wa_it = wa4 + it * 128;
    const float* wa_nx = wa4 + (it < 3 ? it + 1 : 3) * 128;

    hipMemsetAsync(hist16, 0, H16BINS * 4, stream);
    alpha_csr_kernel<<<(NN + 255) / 256, 256, 0, stream>>>(rowptr_s, cspack_s, nodewa,
                                                           relflat, wa_it, alpha_d, hist16, state);
    sel16_kernel<<<1, 1024, 0, stream>>>(state, hist16);
    cand_kernel<<<EE / 256, 256, 0, stream>>>(alpha_d, state, cand_p);
    final_kernel<<<1, 256, 0, stream>>>(alpha_d, csre_d, cand_p, state);

    update_kernel<<<5000, 256, 0, stream>>>(rowptr_d, packed_d, alpha_d, state, x, relflat,
                                            upd, rnxt);
    node_gemm_kernel<<<625, 256, 0, stream>>>(upd, layer_w, layer_b, rcur, tr_w, tr_b,
                                              ln_g, ln_b, x, wa_nx, nodewa, rnxt);
  }
}

// Round 9
// 738.252 us; speedup vs baseline: 2.1324x; 2.1324x over previous
//
#include <hip/hip_runtime.h>
#include <stdint.h>

#define NN 20000
#define EE 320000
#define FF 64
#define ROW 128              // B*F
#define KTOP 160000
#define NEG_SLOPE 0.2f
#define LN_EPS 1e-5f
#define H16BINS 16384        // (u>>12) - (120<<11), clamped: covers alpha in [2^-7, 1]
#define HBASE (120 << 11)
#define CCAP 16384

__device__ __forceinline__ unsigned int bin_of(unsigned int u) {
  int b = (int)(u >> 12) - HBASE;
  b = b < 0 ? 0 : (b > (H16BINS - 1) ? (H16BINS - 1) : b);
  return (unsigned int)b;
}

// ---------- precompute: rel table [4096] and wa[4][128] ----------
__global__ void precompute_kernel(const float* __restrict__ query,
                                  const float* __restrict__ rel_w,
                                  const float* __restrict__ rel_b,
                                  const float* __restrict__ W,
                                  const float* __restrict__ a,
                                  float* __restrict__ relflat,
                                  float* __restrict__ wa4) {
  int t = blockIdx.x * blockDim.x + threadIdx.x;
  if (t < 4096) {
    int bq = t >> 11, c = t & 2047;
    const float* q = query + bq * FF;
    const float* w = rel_w + (size_t)c * FF;
    float s = rel_b[c];
#pragma unroll
    for (int f = 0; f < FF; f++) s += q[f] * w[f];
    relflat[t] = s;
  }
  if (t < 512) {
    int i = t >> 7, j = t & 127;
    const float* av = a + i * FF;
    const float* w = W + (size_t)j * FF;
    float s = 0.f;
#pragma unroll
    for (int f = 0; f < FF; f++) s += w[f] * av[f];
    wa4[t] = s;
  }
}

// ---------- CSR builds (once per launch) ----------
__global__ void degcnt_kernel(const int* __restrict__ esrc, const int* __restrict__ edst,
                              unsigned int* __restrict__ deg_s, unsigned int* __restrict__ deg_d) {
  int e = blockIdx.x * blockDim.x + threadIdx.x;
  if (e < EE) {
    atomicAdd(deg_s + esrc[e], 1u);
    atomicAdd(deg_d + edst[e], 1u);
  }
}

__global__ void scan_kernel(const unsigned int* __restrict__ deg,
                            unsigned int* __restrict__ rowptr,
                            unsigned int* __restrict__ rowfill) {
  __shared__ unsigned int sh[1024];
  int t = threadIdx.x;
  const int PER = 20;  // 1024*20 >= NN
  unsigned int loc[PER];
  unsigned int sum = 0;
  int base = t * PER;
#pragma unroll
  for (int i = 0; i < PER; i++) {
    int n = base + i;
    unsigned int d = (n < NN) ? deg[n] : 0u;
    loc[i] = sum;
    sum += d;
  }
  sh[t] = sum;
  __syncthreads();
  for (int o = 1; o < 1024; o <<= 1) {
    unsigned int v = (t >= o) ? sh[t - o] : 0u;
    __syncthreads();
    sh[t] += v;
    __syncthreads();
  }
  unsigned int excl = sh[t] - sum;
#pragma unroll
  for (int i = 0; i < PER; i++) {
    int n = base + i;
    if (n < NN) {
      unsigned int rp = excl + loc[i];
      rowptr[n] = rp;
      rowfill[n] = rp;
    }
  }
  if (t == 1023) rowptr[NN] = EE;
}

// fill both CSRs; src entries packed as e | (r<<19)
__global__ void fill_kernel(const int* __restrict__ esrc, const int* __restrict__ edst,
                            const int* __restrict__ rix,
                            unsigned int* __restrict__ rowfill_s, unsigned int* __restrict__ rowfill_d,
                            unsigned int* __restrict__ cspack_s, int* __restrict__ csre_d) {
  int e = blockIdx.x * blockDim.x + threadIdx.x;
  if (e < EE) {
    unsigned int r = (unsigned int)rix[e];
    unsigned int ss = atomicAdd(rowfill_s + esrc[e], 1u);
    cspack_s[ss] = (unsigned int)e | (r << 19);
    unsigned int sd = atomicAdd(rowfill_d + edst[e], 1u);
    csre_d[sd] = e;
  }
}

// packed_d[p] = src | (r<<20) in dst-CSR order; pos_d[e] = p (inverse perm)
__global__ void gatherd_kernel(const int* __restrict__ csre_d, const int* __restrict__ esrc,
                               const int* __restrict__ rix, unsigned int* __restrict__ packed_d,
                               unsigned int* __restrict__ pos_d) {
  int p = blockIdx.x * blockDim.x + threadIdx.x;
  if (p < EE) {
    int e = csre_d[p];
    packed_d[p] = (unsigned int)esrc[e] | ((unsigned int)rix[e] << 20);
    pos_d[e] = (unsigned int)p;
  }
}

// rewrite cspack_s: replace embedded e with dst-CSR position (both < 2^19)
__global__ void repack_kernel(unsigned int* __restrict__ cspack_s,
                              const unsigned int* __restrict__ pos_d) {
  int i = blockIdx.x * blockDim.x + threadIdx.x;
  if (i < EE) {
    unsigned int cs = cspack_s[i];
    cspack_s[i] = pos_d[cs & 0x7FFFFu] | (cs & 0xFFF80000u);
  }
}

// ---------- init: racc0 and nodewa ----------
__global__ void readout_kernel(const float* __restrict__ x, float* __restrict__ racc) {
  int j = threadIdx.x;  // 0..127
  float acc = 0.f;
  for (int n = blockIdx.x; n < NN; n += gridDim.x) acc += x[(size_t)n * ROW + j];
  atomicAdd(racc + j, acc);
}

__global__ void nodewa_kernel(const float* __restrict__ x, const float* __restrict__ wa,
                              float* __restrict__ nodewa) {
  int wave = threadIdx.x >> 6, lane = threadIdx.x & 63;
  float w0 = wa[lane], w1 = wa[64 + lane];
  for (int n = blockIdx.x * 4 + wave; n < NN; n += gridDim.x * 4) {
    float s = x[(size_t)n * ROW + lane] * w0 + x[(size_t)n * ROW + 64 + lane] * w1;
#pragma unroll
    for (int off = 32; off > 0; off >>= 1) s += __shfl_xor(s, off, 64);
    if (lane == 0) nodewa[n] = s;
  }
}

// ---------- per-src softmax; alpha written in dst-CSR order; 14-bit LDS hist ----------
// state: [0]=bin [1]=krem [2]=T [3]=need [4]=spare [5]=candCnt
__global__ __launch_bounds__(256) void alpha_csr_kernel(
    const unsigned int* __restrict__ rowptr_s, const unsigned int* __restrict__ cspack_s,
    const float* __restrict__ nodewa, const float* __restrict__ relflat,
    const float* __restrict__ wa, float* __restrict__ alpha_d,
    unsigned int* __restrict__ hist16, unsigned int* __restrict__ state) {
  __shared__ float relwa_sh[32];
  __shared__ unsigned int h16[H16BINS];  // 64 KB
  int t = threadIdx.x;
  for (int i = t; i < H16BINS; i += 256) h16[i] = 0u;
  if (t < 32) {
    float s = 0.f;
    const float4* rf = (const float4*)(relflat + t * ROW);
    const float4* wf = (const float4*)wa;
#pragma unroll 8
    for (int j = 0; j < 32; j++) {
      float4 r4 = rf[j], w4 = wf[j];
      s += r4.x * w4.x + r4.y * w4.y + r4.z * w4.z + r4.w * w4.w;
    }
    relwa_sh[t] = s;
  }
  if (blockIdx.x == 0 && t == 255) { state[0] = 0u; state[1] = KTOP; }
  __syncthreads();
  int n = blockIdx.x * 256 + t;
  if (n < NN) {
    unsigned int p0 = rowptr_s[n], p1 = rowptr_s[n + 1];
    float nw = nodewa[n];
    float denom = 0.f;
    for (unsigned int p = p0; p < p1; p++) {
      unsigned int cs = cspack_s[p];
      float v = nw + relwa_sh[cs >> 19];
      v = v > 0.f ? v : NEG_SLOPE * v;
      denom += expf(v);
    }
    float inv = 1.0f / denom;
    for (unsigned int p = p0; p < p1; p++) {
      unsigned int cs = cspack_s[p];
      float v = nw + relwa_sh[cs >> 19];
      v = v > 0.f ? v : NEG_SLOPE * v;
      float av = expf(v) * inv;
      alpha_d[cs & 0x7FFFFu] = av;
      atomicAdd(&h16[bin_of(__float_as_uint(av))], 1u);
    }
  }
  __syncthreads();
  for (int i = t; i < H16BINS; i += 256) {
    unsigned int c = h16[i];
    if (c) atomicAdd(hist16 + i, c);
  }
}

// ---------- select threshold bin over 16384 bins (1 block, 1024 threads) ----------
__global__ void sel16_kernel(unsigned int* __restrict__ state, const unsigned int* __restrict__ hist16) {
  __shared__ unsigned int sh[1024];
  int t = threadIdx.x;
  unsigned int s = 0;
  const unsigned int* hp = hist16 + t * (H16BINS / 1024);
#pragma unroll
  for (int i = 0; i < H16BINS / 1024; i++) s += hp[i];
  sh[t] = s;
  __syncthreads();
  for (int o = 1; o < 1024; o <<= 1) {
    unsigned int v = (t >= o) ? sh[t - o] : 0u;
    __syncthreads();
    sh[t] += v;
    __syncthreads();
  }
  unsigned int incl = sh[t];
  unsigned int total = sh[1023];
  unsigned int krem = state[1];
  unsigned int cumAbove = total - incl;
  if (t == 0) state[5] = 0u;
  if (cumAbove < krem && cumAbove + s >= krem) {
    unsigned int cum = cumAbove;
    for (int b = H16BINS / 1024 - 1; b >= 0; b--) {
      unsigned int c = hist16[t * (H16BINS / 1024) + b];
      if (cum + c >= krem) {
        state[0] = (unsigned int)(t * (H16BINS / 1024) + b);
        state[1] = krem - cum;
        break;
      }
      cum += c;
    }
  }
}

// ---------- collect boundary-bin candidates (block-aggregated append) ----------
__global__ void cand_kernel(const float* __restrict__ alpha_d, unsigned int* __restrict__ state,
                            int* __restrict__ cand_p) {
  __shared__ int lbuf[256];
  __shared__ unsigned int lcnt;
  __shared__ unsigned int gbase;
  int t = threadIdx.x;
  if (t == 0) lcnt = 0u;
  __syncthreads();
  int p = blockIdx.x * 256 + t;
  if (p < EE) {
    unsigned int u = __float_as_uint(alpha_d[p]);
    if (bin_of(u) == state[0]) {
      unsigned int idx = atomicAdd(&lcnt, 1u);
      lbuf[idx] = p;
    }
  }
  __syncthreads();
  if (t == 0 && lcnt) gbase = atomicAdd(state + 5, lcnt);
  __syncthreads();
  if (t < (int)lcnt) {
    unsigned int pos = gbase + t;
    if (pos < CCAP) cand_p[pos] = lbuf[t];
  }
}

// ---------- exact threshold via low-12-bit hist + tiny tie-break (1 block) ----------
__global__ void final_kernel(float* __restrict__ alpha_d, const int* __restrict__ csre_d,
                             const int* __restrict__ cand_p, unsigned int* __restrict__ state) {
  __shared__ unsigned int hlow[4096];   // 16 KB
  __shared__ unsigned int psum[256];
  __shared__ int tiebuf[2048];
  __shared__ unsigned int tcnt;
  __shared__ unsigned int sT, sNeed;
  int t = threadIdx.x;
  unsigned int cnt = state[5];
  if (cnt > CCAP) cnt = CCAP;
  unsigned int krem = state[1];
  for (int i = t; i < 4096; i += 256) hlow[i] = 0u;
  if (t == 0) { tcnt = 0u; sT = 0u; sNeed = 0xFFFFFFFFu; }
  __syncthreads();
  for (unsigned int i = t; i < cnt; i += 256)
    atomicAdd(&hlow[__float_as_uint(alpha_d[cand_p[i]]) & 0xFFFu], 1u);
  __syncthreads();
  // chunk sums: thread t covers bins [t*16, t*16+16)
  unsigned int s = 0;
#pragma unroll
  for (int i = 0; i < 16; i++) s += hlow[t * 16 + i];
  psum[t] = s;
  __syncthreads();
  for (int o = 1; o < 256; o <<= 1) {
    unsigned int v = (t >= o) ? psum[t - o] : 0u;
    __syncthreads();
    psum[t] += v;
    __syncthreads();
  }
  unsigned int total = psum[255];
  unsigned int above_chunk = total - psum[t];   // strictly-higher chunks
  if (above_chunk < krem && above_chunk + s >= krem) {
    unsigned int cum = above_chunk;
    for (int b = 15; b >= 0; b--) {
      unsigned int c = hlow[t * 16 + b];
      if (cum + c >= krem) {
        // BUGFIX (R8): reconstruct full bits with HBASE rebased bin index
        sT = ((state[0] + (unsigned int)HBASE) << 12) | (unsigned int)(t * 16 + b);
        sNeed = krem - cum;
        break;
      }
      cum += c;
    }
  }
  __syncthreads();
  unsigned int T = sT, need = sNeed;
  if (t == 0) { state[2] = T; state[3] = need; }
  // ties at exactly T
  for (unsigned int i = t; i < cnt; i += 256) {
    int p = cand_p[i];
    if (__float_as_uint(alpha_d[p]) == T) {
      unsigned int idx = atomicAdd(&tcnt, 1u);
      if (idx < 2048) tiebuf[idx] = p;
    }
  }
  __syncthreads();
  unsigned int tc = tcnt;
  if (tc > 2048) tc = 2048;
  if (tc > need) {
    // keep lowest original edge index first (jax.lax.top_k order)
    for (unsigned int i = t; i < tc; i += 256) {
      int p = tiebuf[i];
      int e_i = csre_d[p];
      unsigned int rank = 0;
      for (unsigned int j = 0; j < tc; j++) rank += (csre_d[tiebuf[j]] < e_i) ? 1u : 0u;
      if (rank >= need) alpha_d[p] = 0.f;  // excluded tie -> fails u>=T test
    }
  }
}

// ---------- gather-reduce update: 4 edges x 16 lanes per wave, fused top-k test ----------
__global__ __launch_bounds__(256) void update_kernel(const unsigned int* __restrict__ rowptr_d,
                                                     const unsigned int* __restrict__ packed_d,
                                                     const float* __restrict__ alpha_d,
                                                     const unsigned int* __restrict__ state,
                                                     const float* __restrict__ x,
                                                     const float* __restrict__ relflat,
                                                     float* __restrict__ upd,
                                                     float* __restrict__ racc_next) {
  __shared__ float relf[32 * 132];
  int t = threadIdx.x;
  if (blockIdx.x == 0 && t < 128) racc_next[t] = 0.f;
#pragma unroll
  for (int i = 0; i < 4; i++) {
    int q = t + i * 256;                 // float4 idx 0..1023
    int r = q >> 5, kq = q & 31;
    float4 v = ((const float4*)relflat)[q];
    *(float4*)(relf + r * 132 + kq * 4) = v;
  }
  __syncthreads();
  unsigned int T = state[2];
  int wave = t >> 6, lane = t & 63;
  int g = lane >> 4, l = lane & 15;
  int n = blockIdx.x * 4 + wave;
  if (n >= NN) return;
  unsigned int p0 = rowptr_d[n], p1 = rowptr_d[n + 1];
  float4 A0 = {0.f, 0.f, 0.f, 0.f}, A1 = {0.f, 0.f, 0.f, 0.f};
  for (unsigned int base = p0 + g; base < p1; base += 4) {
    float w = alpha_d[base];
    if (__float_as_uint(w) < T) continue;   // top-k mask (zeroed ties fail too)
    unsigned int up = packed_d[base];
    unsigned int src = up & 0xFFFFFu;
    unsigned int r = up >> 20;
    const float* xr = x + (size_t)src * ROW + l * 8;
    const float* rr = relf + r * 132 + l * 8;
    float4 xv0 = *(const float4*)xr;
    float4 xv1 = *(const float4*)(xr + 4);
    float4 rv0 = *(const float4*)rr;
    float4 rv1 = *(const float4*)(rr + 4);
    A0.x += w * (xv0.x + rv0.x); A0.y += w * (xv0.y + rv0.y);
    A0.z += w * (xv0.z + rv0.z); A0.w += w * (xv0.w + rv0.w);
    A1.x += w * (xv1.x + rv1.x); A1.y += w * (xv1.y + rv1.y);
    A1.z += w * (xv1.z + rv1.z); A1.w += w * (xv1.w + rv1.w);
  }
#pragma unroll
  for (int off = 16; off <= 32; off <<= 1) {
    A0.x += __shfl_xor(A0.x, off, 64); A0.y += __shfl_xor(A0.y, off, 64);
    A0.z += __shfl_xor(A0.z, off, 64); A0.w += __shfl_xor(A0.w, off, 64);
    A1.x += __shfl_xor(A1.x, off, 64); A1.y += __shfl_xor(A1.y, off, 64);
    A1.z += __shfl_xor(A1.z, off, 64); A1.w += __shfl_xor(A1.w, off, 64);
  }
  if (g == 0) {
    const float* xn = x + (size_t)n * ROW + l * 8;
    float4 xs0 = *(const float4*)xn;
    float4 xs1 = *(const float4*)(xn + 4);
    float4 o0 = {A0.x + xs0.x, A0.y + xs0.y, A0.z + xs0.z, A0.w + xs0.w};
    float4 o1 = {A1.x + xs1.x, A1.y + xs1.y, A1.z + xs1.z, A1.w + xs1.w};
    float* on = upd + (size_t)n * ROW + l * 8;
    *(float4*)on = o0;
    *(float4*)(on + 4) = o1;
  }
}

// ---------- node GEMM: [64 rows x 128] @ [128 x 64] + trt + LN + ELU + residual ----------
__global__ __launch_bounds__(256) void node_gemm_kernel(const float* __restrict__ upd,
                                                        const float* __restrict__ layer_w,
                                                        const float* __restrict__ layer_b,
                                                        const float* __restrict__ racc_cur,
                                                        const float* __restrict__ tr_w,
                                                        const float* __restrict__ tr_b,
                                                        const float* __restrict__ ln_g,
                                                        const float* __restrict__ ln_b,
                                                        float* __restrict__ x,
                                                        const float* __restrict__ wa_next,
                                                        float* __restrict__ nodewa,
                                                        float* __restrict__ racc_next) {
  __shared__ float As[64 * 132];
  __shared__ float Ws[64 * 132];
  __shared__ float trt_sh[128];
  __shared__ float racc_sh[128];
  __shared__ float nodewa_sh[32];
  int t = threadIdx.x;
  int n0 = blockIdx.x * 32;
  // per-block trt (readout linear) with layer_b folded in
  if (t < 128) {
    int b = t >> 6, f = t & 63;
    const float invN = 1.0f / (float)NN;
    float s = tr_b[f] + layer_b[f];
    const float* rr = racc_cur + b * 64;
    const float* tw = tr_w + f * 64;
#pragma unroll 16
    for (int gg = 0; gg < 64; gg++) s += rr[gg] * invN * tw[gg];
    trt_sh[t] = s;
    racc_sh[t] = 0.f;
  }
  if (t < 32) nodewa_sh[t] = 0.f;
  // stage A = [x | upd] rows, stride 132
#pragma unroll
  for (int i = 0; i < 4; i++) {
    int v = t + i * 256;                  // 0..1023 float4s
    int nl = v >> 5, i4 = v & 31;
    int b = i4 >> 4, kq = i4 & 15;
    int m = nl * 2 + b;
    float4 xv = ((const float4*)x)[n0 * 32 + v];
    *(float4*)(As + m * 132 + kq * 4) = xv;
  }
#pragma unroll
  for (int i = 0; i < 4; i++) {
    int v = t + i * 256;
    int nl = v >> 5, i4 = v & 31;
    int b = i4 >> 4, kq = i4 & 15;
    int m = nl * 2 + b;
    float4 uv = ((const float4*)upd)[n0 * 32 + v];
    *(float4*)(As + m * 132 + 64 + kq * 4) = uv;
  }
  // stage W swizzled: quad q of row f at position q ^ ((f>>2)&7)
#pragma unroll
  for (int i = 0; i < 8; i++) {
    int Q = t + i * 256;                  // 0..2047
    int f = Q >> 5, q = Q & 31;
    float4 wv = ((const float4*)layer_w)[Q];
    *(float4*)(Ws + f * 132 + ((q ^ ((f >> 2) & 7)) << 2)) = wv;
  }
  __syncthreads();
  int tx = t & 15, ty = t >> 4;
  float acc[4][4] = {};
  const float* Abase = As + (ty * 4) * 132;
  const float* Wbase = Ws + (tx * 4) * 132;
  int wswz = tx & 7;
#pragma unroll 4
  for (int kq = 0; kq < 32; kq++) {
    float4 a0 = *(const float4*)(Abase + 0 * 132 + kq * 4);
    float4 a1 = *(const float4*)(Abase + 1 * 132 + kq * 4);
    float4 a2 = *(const float4*)(Abase + 2 * 132 + kq * 4);
    float4 a3 = *(const float4*)(Abase + 3 * 132 + kq * 4);
    int wq = (kq ^ wswz) << 2;
    float4 w0 = *(const float4*)(Wbase + 0 * 132 + wq);
    float4 w1 = *(const float4*)(Wbase + 1 * 132 + wq);
    float4 w2 = *(const float4*)(Wbase + 2 * 132 + wq);
    float4 w3 = *(const float4*)(Wbase + 3 * 132 + wq);
#define DOT4(A, W) (A.x * W.x + A.y * W.y + A.z * W.z + A.w * W.w)
    acc[0][0] += DOT4(a0, w0); acc[0][1] += DOT4(a0, w1); acc[0][2] += DOT4(a0, w2); acc[0][3] += DOT4(a0, w3);
    acc[1][0] += DOT4(a1, w0); acc[1][1] += DOT4(a1, w1); acc[1][2] += DOT4(a1, w2); acc[1][3] += DOT4(a1, w3);
    acc[2][0] += DOT4(a2, w0); acc[2][1] += DOT4(a2, w1); acc[2][2] += DOT4(a2, w2); acc[2][3] += DOT4(a2, w3);
    acc[3][0] += DOT4(a3, w0); acc[3][1] += DOT4(a3, w1); acc[3][2] += DOT4(a3, w2); acc[3][3] += DOT4(a3, w3);
#undef DOT4
  }
  // add trt (+layer_b); rows m = ty*4+r, b = r&1
#pragma unroll
  for (int r = 0; r < 4; r++) {
    const float* tp = trt_sh + ((r & 1) << 6) + tx * 4;
#pragma unroll
    for (int c = 0; c < 4; c++) acc[r][c] += tp[c];
  }
  // LN stats over 64 f: reduce across 16 tx lanes
  float s[4], qq[4];
#pragma unroll
  for (int r = 0; r < 4; r++) {
    s[r] = acc[r][0] + acc[r][1] + acc[r][2] + acc[r][3];
    qq[r] = acc[r][0] * acc[r][0] + acc[r][1] * acc[r][1] + acc[r][2] * acc[r][2] + acc[r][3] * acc[r][3];
  }
#pragma unroll
  for (int off = 1; off < 16; off <<= 1) {
#pragma unroll
    for (int r = 0; r < 4; r++) {
      s[r] += __shfl_xor(s[r], off, 64);
      qq[r] += __shfl_xor(qq[r], off, 64);
    }
  }
  float4 g4 = ((const float4*)ln_g)[tx];
  float4 b4 = ((const float4*)ln_b)[tx];
  float4 wn = ((const float4*)wa_next)[tx];        // b=0 cols
  float4 wn1 = ((const float4*)wa_next)[16 + tx];  // b=1 cols
  const float invF = 1.0f / (float)FF;
  float nwc[2] = {0.f, 0.f};  // per local node (ty*2, ty*2+1)
#pragma unroll
  for (int r = 0; r < 4; r++) {
    float mu = s[r] * invF;
    float var = qq[r] * invF - mu * mu;
    float rstd = 1.0f / sqrtf(var + LN_EPS);
    int m = ty * 4 + r;
    int nl = m >> 1, b = m & 1;
    // residual x from global (still old values)
    float4 xo = ((const float4*)x)[(n0 + nl) * 32 + b * 16 + tx];
    float o0 = (acc[r][0] - mu) * rstd * g4.x + b4.x;
    float o1 = (acc[r][1] - mu) * rstd * g4.y + b4.y;
    float o2 = (acc[r][2] - mu) * rstd * g4.z + b4.z;
    float o3 = (acc[r][3] - mu) * rstd * g4.w + b4.w;
    float4 y;
    y.x = (o0 > 0.f ? o0 : expm1f(o0)) + xo.x;
    y.y = (o1 > 0.f ? o1 : expm1f(o1)) + xo.y;
    y.z = (o2 > 0.f ? o2 : expm1f(o2)) + xo.z;
    y.w = (o3 > 0.f ? o3 : expm1f(o3)) + xo.w;
    ((float4*)x)[(n0 + nl) * 32 + b * 16 + tx] = y;
    // racc accumulation
    float* rs = racc_sh + (b << 6) + tx * 4;
    atomicAdd(rs + 0, y.x); atomicAdd(rs + 1, y.y);
    atomicAdd(rs + 2, y.z); atomicAdd(rs + 3, y.w);
    // nodewa contribution
    float4 w = b ? wn1 : wn;
    nwc[r >> 1] += y.x * w.x + y.y * w.y + y.z * w.z + y.w * w.w;
  }
  atomicAdd(&nodewa_sh[ty * 2 + 0], nwc[0]);
  atomicAdd(&nodewa_sh[ty * 2 + 1], nwc[1]);
  __syncthreads();
  if (t < 128) atomicAdd(racc_next + t, racc_sh[t]);
  if (t < 32) nodewa[n0 + t] = nodewa_sh[t];
}

extern "C" void kernel_launch(void* const* d_in, const int* in_sizes, int n_in,
                              void* d_out, int out_size, void* d_ws, size_t ws_size,
                              hipStream_t stream) {
  const int* ei = (const int*)d_in[0];
  const int* esrc = ei;
  const int* edst = ei + EE;
  const int* rix = (const int*)d_in[1];
  const float* boundary = (const float*)d_in[2];
  const float* query = (const float*)d_in[3];
  const float* rel_w = (const float*)d_in[4];
  const float* rel_b = (const float*)d_in[5];
  const float* layer_w = (const float*)d_in[6];
  const float* layer_b = (const float*)d_in[7];
  const float* tr_w = (const float*)d_in[8];
  const float* tr_b = (const float*)d_in[9];
  const float* Wm = (const float*)d_in[10];
  const float* av = (const float*)d_in[11];
  const float* ln_g = (const float*)d_in[12];
  const float* ln_b = (const float*)d_in[13];
  float* x = (float*)d_out;

  char* ws = (char*)d_ws;
  size_t off = 0;
  auto allocf = [&](size_t n) -> float* {
    float* p = (float*)(ws + off);
    off += ((n * 4 + 255) / 256) * 256;
    return p;
  };
  auto allocu = [&](size_t n) -> unsigned int* {
    unsigned int* p = (unsigned int*)(ws + off);
    off += ((n * 4 + 255) / 256) * 256;
    return p;
  };
  float* relflat = allocf(4096);
  float* wa4 = allocf(512);
  float* alpha_d = allocf(EE);       // alpha in dst-CSR order
  float* upd = allocf((size_t)NN * ROW);
  float* racc0 = allocf(128);
  float* racc1 = allocf(128);
  float* nodewa = allocf(NN);
  unsigned int* hist16 = allocu(H16BINS);
  unsigned int* state = allocu(8);
  unsigned int* deg_s = allocu(NN);
  unsigned int* deg_d = allocu(NN);
  unsigned int* rowptr_s = allocu(NN + 1);
  unsigned int* rowptr_d = allocu(NN + 1);
  unsigned int* rowfill_s = allocu(NN);
  unsigned int* rowfill_d = allocu(NN);
  unsigned int* cspack_s = allocu(EE);
  int* csre_d = (int*)allocu(EE);
  unsigned int* packed_d = allocu(EE);
  unsigned int* pos_d = allocu(EE);
  int* cand_p = (int*)allocu(CCAP);
  float* rbuf[2] = {racc0, racc1};

  hipMemcpyAsync(x, boundary, (size_t)NN * ROW * 4, hipMemcpyDeviceToDevice, stream);
  hipMemsetAsync(deg_s, 0, NN * 4, stream);
  hipMemsetAsync(deg_d, 0, NN * 4, stream);
  hipMemsetAsync(racc0, 0, 128 * 4, stream);
  precompute_kernel<<<16, 256, 0, stream>>>(query, rel_w, rel_b, Wm, av, relflat, wa4);

  // CSR builds (edge_index constant for this launch)
  degcnt_kernel<<<EE / 256, 256, 0, stream>>>(esrc, edst, deg_s, deg_d);
  scan_kernel<<<1, 1024, 0, stream>>>(deg_s, rowptr_s, rowfill_s);
  scan_kernel<<<1, 1024, 0, stream>>>(deg_d, rowptr_d, rowfill_d);
  fill_kernel<<<EE / 256, 256, 0, stream>>>(esrc, edst, rix, rowfill_s, rowfill_d, cspack_s, csre_d);
  gatherd_kernel<<<EE / 256, 256, 0, stream>>>(csre_d, esrc, rix, packed_d, pos_d);
  repack_kernel<<<EE / 256, 256, 0, stream>>>(cspack_s, pos_d);

  // iter-0 readout sum and nodewa
  readout_kernel<<<256, 128, 0, stream>>>(x, racc0);
  nodewa_kernel<<<1250, 256, 0, stream>>>(x, wa4, nodewa);

  for (int it = 0; it < 4; it++) {
    float* rcur = rbuf[it & 1];
    float* rnxt = rbuf[(it + 1) & 1];
    const float* wa_it = wa4 + it * 128;
    const float* wa_nx = wa4 + (it < 3 ? it + 1 : 3) * 128;

    hipMemsetAsync(hist16, 0, H16BINS * 4, stream);
    alpha_csr_kernel<<<(NN + 255) / 256, 256, 0, stream>>>(rowptr_s, cspack_s, nodewa,
                                                           relflat, wa_it, alpha_d, hist16, state);
    sel16_kernel<<<1, 1024, 0, stream>>>(state, hist16);
    cand_kernel<<<EE / 256, 256, 0, stream>>>(alpha_d, state, cand_p);
    final_kernel<<<1, 256, 0, stream>>>(alpha_d, csre_d, cand_p, state);

    update_kernel<<<5000, 256, 0, stream>>>(rowptr_d, packed_d, alpha_d, state, x, relflat,
                                            upd, rnxt);
    node_gemm_kernel<<<625, 256, 0, stream>>>(upd, layer_w, layer_b, rcur, tr_w, tr_b,
                                              ln_g, ln_b, x, wa_nx, nodewa, rnxt);
  }
}

// Round 10
// 694.862 us; speedup vs baseline: 2.2656x; 1.0624x over previous
//
#include <hip/hip_runtime.h>
#include <stdint.h>

#define NN 20000
#define EE 320000
#define FF 64
#define ROW 128              // B*F
#define KTOP 160000
#define NEG_SLOPE 0.2f
#define LN_EPS 1e-5f
#define H16BINS 16384        // (u>>12) - (120<<11), clamped: covers alpha in [2^-7, 1]
#define HBASE (120 << 11)
#define CCAP 16384
#define ASTR 136             // bf16 stride for MFMA LDS tiles (16B-aligned frag reads)

typedef __attribute__((ext_vector_type(8))) short short8;
typedef __attribute__((ext_vector_type(4))) float f32x4;

__device__ __forceinline__ unsigned int bin_of(unsigned int u) {
  int b = (int)(u >> 12) - HBASE;
  b = b < 0 ? 0 : (b > (H16BINS - 1) ? (H16BINS - 1) : b);
  return (unsigned int)b;
}

__device__ __forceinline__ unsigned int f2bf(float v) {
  unsigned int u = __float_as_uint(v);
  return (u + 0x7FFFu + ((u >> 16) & 1u)) >> 16;   // RNE
}

__device__ __forceinline__ unsigned long long pack4bf(float4 v) {
  unsigned long long a = (unsigned long long)f2bf(v.x);
  a |= (unsigned long long)f2bf(v.y) << 16;
  a |= (unsigned long long)f2bf(v.z) << 32;
  a |= (unsigned long long)f2bf(v.w) << 48;
  return a;
}

// ---------- precompute: rel table [4096] and wa[4][128] ----------
__global__ void precompute_kernel(const float* __restrict__ query,
                                  const float* __restrict__ rel_w,
                                  const float* __restrict__ rel_b,
                                  const float* __restrict__ W,
                                  const float* __restrict__ a,
                                  float* __restrict__ relflat,
                                  float* __restrict__ wa4) {
  int t = blockIdx.x * blockDim.x + threadIdx.x;
  if (t < 4096) {
    int bq = t >> 11, c = t & 2047;
    const float* q = query + bq * FF;
    const float* w = rel_w + (size_t)c * FF;
    float s = rel_b[c];
#pragma unroll
    for (int f = 0; f < FF; f++) s += q[f] * w[f];
    relflat[t] = s;
  }
  if (t < 512) {
    int i = t >> 7, j = t & 127;
    const float* av = a + i * FF;
    const float* w = W + (size_t)j * FF;
    float s = 0.f;
#pragma unroll
    for (int f = 0; f < FF; f++) s += w[f] * av[f];
    wa4[t] = s;
  }
}

// ---------- CSR builds (once per launch) ----------
__global__ void degcnt_kernel(const int* __restrict__ esrc, const int* __restrict__ edst,
                              unsigned int* __restrict__ deg_s, unsigned int* __restrict__ deg_d) {
  int e = blockIdx.x * blockDim.x + threadIdx.x;
  if (e < EE) {
    atomicAdd(deg_s + esrc[e], 1u);
    atomicAdd(deg_d + edst[e], 1u);
  }
}

__global__ void scan_kernel(const unsigned int* __restrict__ deg,
                            unsigned int* __restrict__ rowptr,
                            unsigned int* __restrict__ rowfill) {
  __shared__ unsigned int sh[1024];
  int t = threadIdx.x;
  const int PER = 20;  // 1024*20 >= NN
  unsigned int loc[PER];
  unsigned int sum = 0;
  int base = t * PER;
#pragma unroll
  for (int i = 0; i < PER; i++) {
    int n = base + i;
    unsigned int d = (n < NN) ? deg[n] : 0u;
    loc[i] = sum;
    sum += d;
  }
  sh[t] = sum;
  __syncthreads();
  for (int o = 1; o < 1024; o <<= 1) {
    unsigned int v = (t >= o) ? sh[t - o] : 0u;
    __syncthreads();
    sh[t] += v;
    __syncthreads();
  }
  unsigned int excl = sh[t] - sum;
#pragma unroll
  for (int i = 0; i < PER; i++) {
    int n = base + i;
    if (n < NN) {
      unsigned int rp = excl + loc[i];
      rowptr[n] = rp;
      rowfill[n] = rp;
    }
  }
  if (t == 1023) rowptr[NN] = EE;
}

// fill both CSRs; src entries packed as e | (r<<19)
__global__ void fill_kernel(const int* __restrict__ esrc, const int* __restrict__ edst,
                            const int* __restrict__ rix,
                            unsigned int* __restrict__ rowfill_s, unsigned int* __restrict__ rowfill_d,
                            unsigned int* __restrict__ cspack_s, int* __restrict__ csre_d) {
  int e = blockIdx.x * blockDim.x + threadIdx.x;
  if (e < EE) {
    unsigned int r = (unsigned int)rix[e];
    unsigned int ss = atomicAdd(rowfill_s + esrc[e], 1u);
    cspack_s[ss] = (unsigned int)e | (r << 19);
    unsigned int sd = atomicAdd(rowfill_d + edst[e], 1u);
    csre_d[sd] = e;
  }
}

// packed_d[p] = src | (r<<20) in dst-CSR order; pos_d[e] = p (inverse perm)
__global__ void gatherd_kernel(const int* __restrict__ csre_d, const int* __restrict__ esrc,
                               const int* __restrict__ rix, unsigned int* __restrict__ packed_d,
                               unsigned int* __restrict__ pos_d) {
  int p = blockIdx.x * blockDim.x + threadIdx.x;
  if (p < EE) {
    int e = csre_d[p];
    packed_d[p] = (unsigned int)esrc[e] | ((unsigned int)rix[e] << 20);
    pos_d[e] = (unsigned int)p;
  }
}

// rewrite cspack_s: replace embedded e with dst-CSR position (both < 2^19)
__global__ void repack_kernel(unsigned int* __restrict__ cspack_s,
                              const unsigned int* __restrict__ pos_d) {
  int i = blockIdx.x * blockDim.x + threadIdx.x;
  if (i < EE) {
    unsigned int cs = cspack_s[i];
    cspack_s[i] = pos_d[cs & 0x7FFFFu] | (cs & 0xFFF80000u);
  }
}

// ---------- init: racc0 and nodewa ----------
__global__ void readout_kernel(const float* __restrict__ x, float* __restrict__ racc) {
  int j = threadIdx.x;  // 0..127
  float acc = 0.f;
  for (int n = blockIdx.x; n < NN; n += gridDim.x) acc += x[(size_t)n * ROW + j];
  atomicAdd(racc + j, acc);
}

__global__ void nodewa_kernel(const float* __restrict__ x, const float* __restrict__ wa,
                              float* __restrict__ nodewa) {
  int wave = threadIdx.x >> 6, lane = threadIdx.x & 63;
  float w0 = wa[lane], w1 = wa[64 + lane];
  for (int n = blockIdx.x * 4 + wave; n < NN; n += gridDim.x * 4) {
    float s = x[(size_t)n * ROW + lane] * w0 + x[(size_t)n * ROW + 64 + lane] * w1;
#pragma unroll
    for (int off = 32; off > 0; off >>= 1) s += __shfl_xor(s, off, 64);
    if (lane == 0) nodewa[n] = s;
  }
}

// ---------- per-iter trt (readout linear + layer_b folded), 1 block ----------
__global__ void trt_kernel(const float* __restrict__ racc_cur, const float* __restrict__ tr_w,
                           const float* __restrict__ tr_b, const float* __restrict__ layer_b,
                           float* __restrict__ trt_glob) {
  int t = threadIdx.x;  // 0..127
  int b = t >> 6, f = t & 63;
  const float invN = 1.0f / (float)NN;
  float s = tr_b[f] + layer_b[f];
  const float* rr = racc_cur + b * 64;
  const float* tw = tr_w + f * 64;
#pragma unroll 16
  for (int g = 0; g < 64; g++) s += rr[g] * invN * tw[g];
  trt_glob[t] = s;
}

// ---------- per-src softmax; alpha written in dst-CSR order; 14-bit LDS hist ----------
// state: [0]=bin [1]=krem [2]=T [3]=need [4]=spare [5]=candCnt
__global__ __launch_bounds__(256) void alpha_csr_kernel(
    const unsigned int* __restrict__ rowptr_s, const unsigned int* __restrict__ cspack_s,
    const float* __restrict__ nodewa, const float* __restrict__ relflat,
    const float* __restrict__ wa, float* __restrict__ alpha_d,
    unsigned int* __restrict__ hist16, unsigned int* __restrict__ state) {
  __shared__ float relwa_sh[32];
  __shared__ unsigned int h16[H16BINS];  // 64 KB
  int t = threadIdx.x;
  for (int i = t; i < H16BINS; i += 256) h16[i] = 0u;
  if (t < 32) {
    float s = 0.f;
    const float4* rf = (const float4*)(relflat + t * ROW);
    const float4* wf = (const float4*)wa;
#pragma unroll 8
    for (int j = 0; j < 32; j++) {
      float4 r4 = rf[j], w4 = wf[j];
      s += r4.x * w4.x + r4.y * w4.y + r4.z * w4.z + r4.w * w4.w;
    }
    relwa_sh[t] = s;
  }
  if (blockIdx.x == 0 && t == 255) { state[0] = 0u; state[1] = KTOP; }
  __syncthreads();
  int n = blockIdx.x * 256 + t;
  if (n < NN) {
    unsigned int p0 = rowptr_s[n], p1 = rowptr_s[n + 1];
    float nw = nodewa[n];
    float denom = 0.f;
    for (unsigned int p = p0; p < p1; p++) {
      unsigned int cs = cspack_s[p];
      float v = nw + relwa_sh[cs >> 19];
      v = v > 0.f ? v : NEG_SLOPE * v;
      denom += expf(v);
    }
    float inv = 1.0f / denom;
    for (unsigned int p = p0; p < p1; p++) {
      unsigned int cs = cspack_s[p];
      float v = nw + relwa_sh[cs >> 19];
      v = v > 0.f ? v : NEG_SLOPE * v;
      float av = expf(v) * inv;
      alpha_d[cs & 0x7FFFFu] = av;
      atomicAdd(&h16[bin_of(__float_as_uint(av))], 1u);
    }
  }
  __syncthreads();
  for (int i = t; i < H16BINS; i += 256) {
    unsigned int c = h16[i];
    if (c) atomicAdd(hist16 + i, c);
  }
}

// ---------- select threshold bin over 16384 bins; self-zeroes hist16 ----------
__global__ void sel16_kernel(unsigned int* __restrict__ state, unsigned int* __restrict__ hist16) {
  __shared__ unsigned int sh[1024];
  int t = threadIdx.x;
  unsigned int s = 0;
  const unsigned int* hp = hist16 + t * (H16BINS / 1024);
#pragma unroll
  for (int i = 0; i < H16BINS / 1024; i++) s += hp[i];
  sh[t] = s;
  __syncthreads();
  for (int o = 1; o < 1024; o <<= 1) {
    unsigned int v = (t >= o) ? sh[t - o] : 0u;
    __syncthreads();
    sh[t] += v;
    __syncthreads();
  }
  unsigned int incl = sh[t];
  unsigned int total = sh[1023];
  unsigned int krem = state[1];
  unsigned int cumAbove = total - incl;
  if (t == 0) state[5] = 0u;
  if (cumAbove < krem && cumAbove + s >= krem) {
    unsigned int cum = cumAbove;
    for (int b = H16BINS / 1024 - 1; b >= 0; b--) {
      unsigned int c = hist16[t * (H16BINS / 1024) + b];
      if (cum + c >= krem) {
        state[0] = (unsigned int)(t * (H16BINS / 1024) + b);
        state[1] = krem - cum;
        break;
      }
      cum += c;
    }
  }
  // zero own chunk for next iteration (each thread only touches its own bins)
  for (int i = 0; i < H16BINS / 1024; i++) hist16[t * (H16BINS / 1024) + i] = 0u;
}

// ---------- collect boundary-bin candidates (block-aggregated append) ----------
__global__ void cand_kernel(const float* __restrict__ alpha_d, unsigned int* __restrict__ state,
                            int* __restrict__ cand_p) {
  __shared__ int lbuf[256];
  __shared__ unsigned int lcnt;
  __shared__ unsigned int gbase;
  int t = threadIdx.x;
  if (t == 0) lcnt = 0u;
  __syncthreads();
  int p = blockIdx.x * 256 + t;
  if (p < EE) {
    unsigned int u = __float_as_uint(alpha_d[p]);
    if (bin_of(u) == state[0]) {
      unsigned int idx = atomicAdd(&lcnt, 1u);
      lbuf[idx] = p;
    }
  }
  __syncthreads();
  if (t == 0 && lcnt) gbase = atomicAdd(state + 5, lcnt);
  __syncthreads();
  if (t < (int)lcnt) {
    unsigned int pos = gbase + t;
    if (pos < CCAP) cand_p[pos] = lbuf[t];
  }
}

// ---------- exact threshold via low-12-bit hist + tiny tie-break (1 block) ----------
__global__ void final_kernel(float* __restrict__ alpha_d, const int* __restrict__ csre_d,
                             const int* __restrict__ cand_p, unsigned int* __restrict__ state) {
  __shared__ unsigned int hlow[4096];   // 16 KB
  __shared__ unsigned int psum[256];
  __shared__ int tiebuf[2048];
  __shared__ unsigned int tcnt;
  __shared__ unsigned int sT, sNeed;
  int t = threadIdx.x;
  unsigned int cnt = state[5];
  if (cnt > CCAP) cnt = CCAP;
  unsigned int krem = state[1];
  for (int i = t; i < 4096; i += 256) hlow[i] = 0u;
  if (t == 0) { tcnt = 0u; sT = 0u; sNeed = 0xFFFFFFFFu; }
  __syncthreads();
  for (unsigned int i = t; i < cnt; i += 256)
    atomicAdd(&hlow[__float_as_uint(alpha_d[cand_p[i]]) & 0xFFFu], 1u);
  __syncthreads();
  unsigned int s = 0;
#pragma unroll
  for (int i = 0; i < 16; i++) s += hlow[t * 16 + i];
  psum[t] = s;
  __syncthreads();
  for (int o = 1; o < 256; o <<= 1) {
    unsigned int v = (t >= o) ? psum[t - o] : 0u;
    __syncthreads();
    psum[t] += v;
    __syncthreads();
  }
  unsigned int total = psum[255];
  unsigned int above_chunk = total - psum[t];
  if (above_chunk < krem && above_chunk + s >= krem) {
    unsigned int cum = above_chunk;
    for (int b = 15; b >= 0; b--) {
      unsigned int c = hlow[t * 16 + b];
      if (cum + c >= krem) {
        sT = ((state[0] + (unsigned int)HBASE) << 12) | (unsigned int)(t * 16 + b);
        sNeed = krem - cum;
        break;
      }
      cum += c;
    }
  }
  __syncthreads();
  unsigned int T = sT, need = sNeed;
  if (t == 0) { state[2] = T; state[3] = need; }
  for (unsigned int i = t; i < cnt; i += 256) {
    int p = cand_p[i];
    if (__float_as_uint(alpha_d[p]) == T) {
      unsigned int idx = atomicAdd(&tcnt, 1u);
      if (idx < 2048) tiebuf[idx] = p;
    }
  }
  __syncthreads();
  unsigned int tc = tcnt;
  if (tc > 2048) tc = 2048;
  if (tc > need) {
    for (unsigned int i = t; i < tc; i += 256) {
      int p = tiebuf[i];
      int e_i = csre_d[p];
      unsigned int rank = 0;
      for (unsigned int j = 0; j < tc; j++) rank += (csre_d[tiebuf[j]] < e_i) ? 1u : 0u;
      if (rank >= need) alpha_d[p] = 0.f;
    }
  }
}

// ---------- gather-reduce update: 4 edges x 16 lanes per wave, fused top-k test ----------
__global__ __launch_bounds__(256) void update_kernel(const unsigned int* __restrict__ rowptr_d,
                                                     const unsigned int* __restrict__ packed_d,
                                                     const float* __restrict__ alpha_d,
                                                     const unsigned int* __restrict__ state,
                                                     const float* __restrict__ x,
                                                     const float* __restrict__ relflat,
                                                     float* __restrict__ upd,
                                                     float* __restrict__ racc_next) {
  __shared__ float relf[32 * 132];
  int t = threadIdx.x;
  if (blockIdx.x == 0 && t < 128) racc_next[t] = 0.f;
#pragma unroll
  for (int i = 0; i < 4; i++) {
    int q = t + i * 256;
    int r = q >> 5, kq = q & 31;
    float4 v = ((const float4*)relflat)[q];
    *(float4*)(relf + r * 132 + kq * 4) = v;
  }
  __syncthreads();
  unsigned int T = state[2];
  int wave = t >> 6, lane = t & 63;
  int g = lane >> 4, l = lane & 15;
  int n = blockIdx.x * 4 + wave;
  if (n >= NN) return;
  unsigned int p0 = rowptr_d[n], p1 = rowptr_d[n + 1];
  float4 A0 = {0.f, 0.f, 0.f, 0.f}, A1 = {0.f, 0.f, 0.f, 0.f};
  for (unsigned int base = p0 + g; base < p1; base += 4) {
    float w = alpha_d[base];
    if (__float_as_uint(w) < T) continue;
    unsigned int up = packed_d[base];
    unsigned int src = up & 0xFFFFFu;
    unsigned int r = up >> 20;
    const float* xr = x + (size_t)src * ROW + l * 8;
    const float* rr = relf + r * 132 + l * 8;
    float4 xv0 = *(const float4*)xr;
    float4 xv1 = *(const float4*)(xr + 4);
    float4 rv0 = *(const float4*)rr;
    float4 rv1 = *(const float4*)(rr + 4);
    A0.x += w * (xv0.x + rv0.x); A0.y += w * (xv0.y + rv0.y);
    A0.z += w * (xv0.z + rv0.z); A0.w += w * (xv0.w + rv0.w);
    A1.x += w * (xv1.x + rv1.x); A1.y += w * (xv1.y + rv1.y);
    A1.z += w * (xv1.z + rv1.z); A1.w += w * (xv1.w + rv1.w);
  }
#pragma unroll
  for (int off = 16; off <= 32; off <<= 1) {
    A0.x += __shfl_xor(A0.x, off, 64); A0.y += __shfl_xor(A0.y, off, 64);
    A0.z += __shfl_xor(A0.z, off, 64); A0.w += __shfl_xor(A0.w, off, 64);
    A1.x += __shfl_xor(A1.x, off, 64); A1.y += __shfl_xor(A1.y, off, 64);
    A1.z += __shfl_xor(A1.z, off, 64); A1.w += __shfl_xor(A1.w, off, 64);
  }
  if (g == 0) {
    const float* xn = x + (size_t)n * ROW + l * 8;
    float4 xs0 = *(const float4*)xn;
    float4 xs1 = *(const float4*)(xn + 4);
    float4 o0 = {A0.x + xs0.x, A0.y + xs0.y, A0.z + xs0.z, A0.w + xs0.w};
    float4 o1 = {A1.x + xs1.x, A1.y + xs1.y, A1.z + xs1.z, A1.w + xs1.w};
    float* on = upd + (size_t)n * ROW + l * 8;
    *(float4*)on = o0;
    *(float4*)(on + 4) = o1;
  }
}

// ---------- node GEMM via bf16 MFMA + LN + ELU + residual + next-iter racc/nodewa ----------
// block = 32 nodes = 64 M-rows; wave mt owns rows mt*16..+15, all 64 f-cols.
__global__ __launch_bounds__(256) void node_mfma_kernel(const float* __restrict__ upd,
                                                        const float* __restrict__ layer_w,
                                                        const float* __restrict__ trt_glob,
                                                        const float* __restrict__ ln_g,
                                                        const float* __restrict__ ln_b,
                                                        float* __restrict__ x,
                                                        const float* __restrict__ wa_next,
                                                        float* __restrict__ nodewa,
                                                        float* __restrict__ racc_next) {
  __shared__ unsigned short Asb[64 * ASTR];  // 17.4 KB  A=[x|upd] bf16
  __shared__ unsigned short Wsb[64 * ASTR];  // 17.4 KB  layer_w natural [f][c] bf16
  __shared__ float trt_sh[128];
  __shared__ float racc_sh[128];
  int t = threadIdx.x;
  int n0 = blockIdx.x * 32;
  if (t < 128) { trt_sh[t] = trt_glob[t]; racc_sh[t] = 0.f; }
  // stage A: x part (cols 0..63) and upd part (cols 64..127)
#pragma unroll
  for (int i = 0; i < 4; i++) {
    int v = t + i * 256;                  // 0..1023 float4s
    int m = ((v >> 5) << 1) + ((v & 31) >> 4);
    int k = (v & 15) * 4;
    float4 xv = ((const float4*)x)[n0 * 32 + v];
    *(unsigned long long*)(Asb + m * ASTR + k) = pack4bf(xv);
    float4 uv = ((const float4*)upd)[n0 * 32 + v];
    *(unsigned long long*)(Asb + m * ASTR + 64 + k) = pack4bf(uv);
  }
  // stage W (natural [f][c] layout == MFMA B-fragment layout)
#pragma unroll
  for (int i = 0; i < 8; i++) {
    int Q = t + i * 256;                  // 0..2047 float4s
    int f = Q >> 5, c4 = Q & 31;
    float4 wv = ((const float4*)layer_w)[Q];
    *(unsigned long long*)(Wsb + f * ASTR + c4 * 4) = pack4bf(wv);
  }
  __syncthreads();
  int lane = t & 63, mt = t >> 6;
  int l15 = lane & 15, q = lane >> 4;
  const unsigned short* arow = Asb + (mt * 16 + l15) * ASTR + q * 8;
  f32x4 acc[4] = {{0.f, 0.f, 0.f, 0.f}, {0.f, 0.f, 0.f, 0.f},
                  {0.f, 0.f, 0.f, 0.f}, {0.f, 0.f, 0.f, 0.f}};
#pragma unroll
  for (int ks = 0; ks < 4; ks++) {
    short8 a = *(const short8*)(arow + ks * 32);
#pragma unroll
    for (int nt = 0; nt < 4; nt++) {
      short8 b = *(const short8*)(Wsb + (nt * 16 + l15) * ASTR + ks * 32 + q * 8);
      acc[nt] = __builtin_amdgcn_mfma_f32_16x16x32_bf16(a, b, acc[nt], 0, 0, 0);
    }
  }
  // epilogue: C/D layout col = nt*16 + l15, row = mt*16 + q*4 + r
  float g_[4], bta[4], wn0[4], wn1[4], tr0[4], tr1[4];
#pragma unroll
  for (int nt = 0; nt < 4; nt++) {
    int f = nt * 16 + l15;
    g_[nt] = ln_g[f]; bta[nt] = ln_b[f];
    wn0[nt] = wa_next[f]; wn1[nt] = wa_next[64 + f];
    tr0[nt] = trt_sh[f]; tr1[nt] = trt_sh[64 + f];
  }
  const float invF = 1.0f / (float)FF;
  float y[4][4];
#pragma unroll
  for (int r = 0; r < 4; r++) {
    int b = r & 1;
    float o[4];
    float s = 0.f, qq = 0.f;
#pragma unroll
    for (int nt = 0; nt < 4; nt++) {
      float v = acc[nt][r] + (b ? tr1[nt] : tr0[nt]);
      o[nt] = v; s += v; qq += v * v;
    }
#pragma unroll
    for (int off = 1; off < 16; off <<= 1) {
      s += __shfl_xor(s, off, 64);
      qq += __shfl_xor(qq, off, 64);
    }
    float mu = s * invF;
    float var = qq * invF - mu * mu;
    float rstd = 1.0f / sqrtf(var + LN_EPS);
    int nl = mt * 8 + q * 2 + (r >> 1);
    size_t base = (size_t)(n0 + nl) * ROW + b * 64 + l15;
#pragma unroll
    for (int nt = 0; nt < 4; nt++) {
      float xo = x[base + nt * 16];
      float on = (o[nt] - mu) * rstd * g_[nt] + bta[nt];
      float h = on > 0.f ? on : expm1f(on);
      float yy = h + xo;
      y[r][nt] = yy;
      x[base + nt * 16] = yy;
    }
  }
  // racc: rows r and r+2 share (b, f)
#pragma unroll
  for (int b = 0; b < 2; b++) {
#pragma unroll
    for (int nt = 0; nt < 4; nt++) {
      atomicAdd(&racc_sh[b * 64 + nt * 16 + l15], y[b][nt] + y[b + 2][nt]);
    }
  }
  // nodewa: node = mt*8 + q*2 + rp covers rows (2rp: b=0, 2rp+1: b=1)
#pragma unroll
  for (int rp = 0; rp < 2; rp++) {
    float nw = 0.f;
#pragma unroll
    for (int nt = 0; nt < 4; nt++)
      nw += y[2 * rp][nt] * wn0[nt] + y[2 * rp + 1][nt] * wn1[nt];
#pragma unroll
    for (int off = 1; off < 16; off <<= 1) nw += __shfl_xor(nw, off, 64);
    if (l15 == 0) nodewa[n0 + mt * 8 + q * 2 + rp] = nw;
  }
  __syncthreads();
  if (t < 128) atomicAdd(racc_next + t, racc_sh[t]);
}

extern "C" void kernel_launch(void* const* d_in, const int* in_sizes, int n_in,
                              void* d_out, int out_size, void* d_ws, size_t ws_size,
                              hipStream_t stream) {
  const int* ei = (const int*)d_in[0];
  const int* esrc = ei;
  const int* edst = ei + EE;
  const int* rix = (const int*)d_in[1];
  const float* boundary = (const float*)d_in[2];
  const float* query = (const float*)d_in[3];
  const float* rel_w = (const float*)d_in[4];
  const float* rel_b = (const float*)d_in[5];
  const float* layer_w = (const float*)d_in[6];
  const float* layer_b = (const float*)d_in[7];
  const float* tr_w = (const float*)d_in[8];
  const float* tr_b = (const float*)d_in[9];
  const float* Wm = (const float*)d_in[10];
  const float* av = (const float*)d_in[11];
  const float* ln_g = (const float*)d_in[12];
  const float* ln_b = (const float*)d_in[13];
  float* x = (float*)d_out;

  char* ws = (char*)d_ws;
  size_t off = 0;
  auto allocf = [&](size_t n) -> float* {
    float* p = (float*)(ws + off);
    off += ((n * 4 + 255) / 256) * 256;
    return p;
  };
  auto allocu = [&](size_t n) -> unsigned int* {
    unsigned int* p = (unsigned int*)(ws + off);
    off += ((n * 4 + 255) / 256) * 256;
    return p;
  };
  float* relflat = allocf(4096);
  float* wa4 = allocf(512);
  float* alpha_d = allocf(EE);       // alpha in dst-CSR order
  float* upd = allocf((size_t)NN * ROW);
  float* racc0 = allocf(128);
  float* racc1 = allocf(128);
  float* trt_glob = allocf(128);
  float* nodewa = allocf(NN);
  unsigned int* hist16 = allocu(H16BINS);
  unsigned int* state = allocu(8);
  unsigned int* deg_s = allocu(NN);
  unsigned int* deg_d = allocu(NN);
  unsigned int* rowptr_s = allocu(NN + 1);
  unsigned int* rowptr_d = allocu(NN + 1);
  unsigned int* rowfill_s = allocu(NN);
  unsigned int* rowfill_d = allocu(NN);
  unsigned int* cspack_s = allocu(EE);
  int* csre_d = (int*)allocu(EE);
  unsigned int* packed_d = allocu(EE);
  unsigned int* pos_d = allocu(EE);
  int* cand_p = (int*)allocu(CCAP);
  float* rbuf[2] = {racc0, racc1};

  hipMemcpyAsync(x, boundary, (size_t)NN * ROW * 4, hipMemcpyDeviceToDevice, stream);
  hipMemsetAsync(deg_s, 0, NN * 4, stream);
  hipMemsetAsync(deg_d, 0, NN * 4, stream);
  hipMemsetAsync(racc0, 0, 128 * 4, stream);
  hipMemsetAsync(hist16, 0, H16BINS * 4, stream);   // once; sel16 self-zeroes per iter
  precompute_kernel<<<16, 256, 0, stream>>>(query, rel_w, rel_b, Wm, av, relflat, wa4);

  // CSR builds (edge_index constant for this launch)
  degcnt_kernel<<<EE / 256, 256, 0, stream>>>(esrc, edst, deg_s, deg_d);
  scan_kernel<<<1, 1024, 0, stream>>>(deg_s, rowptr_s, rowfill_s);
  scan_kernel<<<1, 1024, 0, stream>>>(deg_d, rowptr_d, rowfill_d);
  fill_kernel<<<EE / 256, 256, 0, stream>>>(esrc, edst, rix, rowfill_s, rowfill_d, cspack_s, csre_d);
  gatherd_kernel<<<EE / 256, 256, 0, stream>>>(csre_d, esrc, rix, packed_d, pos_d);
  repack_kernel<<<EE / 256, 256, 0, stream>>>(cspack_s, pos_d);

  // iter-0 readout sum and nodewa
  readout_kernel<<<256, 128, 0, stream>>>(x, racc0);
  nodewa_kernel<<<1250, 256, 0, stream>>>(x, wa4, nodewa);

  for (int it = 0; it < 4; it++) {
    float* rcur = rbuf[it & 1];
    float* rnxt = rbuf[(it + 1) & 1];
    const float* wa_it = wa4 + it * 128;
    const float* wa_nx = wa4 + (it < 3 ? it + 1 : 3) * 128;

    trt_kernel<<<1, 128, 0, stream>>>(rcur, tr_w, tr_b, layer_b, trt_glob);
    alpha_csr_kernel<<<(NN + 255) / 256, 256, 0, stream>>>(rowptr_s, cspack_s, nodewa,
                                                           relflat, wa_it, alpha_d, hist16, state);
    sel16_kernel<<<1, 1024, 0, stream>>>(state, hist16);
    cand_kernel<<<EE / 256, 256, 0, stream>>>(alpha_d, state, cand_p);
    final_kernel<<<1, 256, 0, stream>>>(alpha_d, csre_d, cand_p, state);

    update_kernel<<<5000, 256, 0, stream>>>(rowptr_d, packed_d, alpha_d, state, x, relflat,
                                            upd, rnxt);
    node_mfma_kernel<<<625, 256, 0, stream>>>(upd, layer_w, trt_glob, ln_g, ln_b, x,
                                              wa_nx, nodewa, rnxt);
  }
}